// Round 21
// baseline (39.923 us; speedup 1.0000x reference)
//
#include <hip/hip_runtime.h>

// ConvAutoEncoder: B=16384, T=64, C=2, D=4
// out = [encoder_out (B*128 f32) | decoded (B*128 f32)]
// Split: k_attn (f16/fdot2 attention -> h in FRAGMENT-MAJOR bf16, dec-out region)
//        k_convdec (conv+decoder, ALL loads lane-contiguous: frag-major weights + h)

typedef __attribute__((ext_vector_type(8))) short bf16x8;
typedef __attribute__((ext_vector_type(4))) float f32x4;
typedef _Float16 h2 __attribute__((ext_vector_type(2)));

__device__ __forceinline__ unsigned short f2bf(float f) {
    unsigned int u = __builtin_bit_cast(unsigned int, f);
    return (unsigned short)((u + 0x7FFFu + ((u >> 16) & 1u)) >> 16);
}
__device__ __forceinline__ unsigned int pack2bf(float a, float b) {
    return (unsigned int)f2bf(a) | ((unsigned int)f2bf(b) << 16);
}

#define SWZ(row) (((row) & 7) << 3)   // ushort-index XOR == byte XOR ((row&7)<<4)

// ---------------- kernel 0: weight prep (fragment-major permutation) ----------------
__global__ void k0_prep(const float* __restrict__ w1, const float* __restrict__ w2,
                        const float* __restrict__ cw, const float* __restrict__ cb,
                        unsigned short* __restrict__ w1c, unsigned short* __restrict__ w2c,
                        unsigned short* __restrict__ wcvc, float* __restrict__ biasf) {
    const int i = blockIdx.x * 256 + threadIdx.x;      // 0..65535
    const int rem = i & 511, ln = rem >> 3, e = rem & 7;
    const int r = ln & 15, g = ln >> 4;
    {   // w1c (65536)
        const int frag = i >> 9, nb = frag >> 2, kb = frag & 3;
        w1c[i] = f2bf(w1[(nb * 16 + r) * 128 + kb * 32 + g * 8 + e]);
    }
    {   // w2c (65536)
        const int frag = i >> 9, mb = frag >> 4, np = frag & 15;
        w2c[i] = f2bf(w2[(mb * 16 + r) * 512 + np * 32 + g * 8 + e]);
    }
    if (i < 32768) {   // wcvc
        const int frag = i >> 9, fb = frag >> 3, kc = frag & 7;
        const int f = fb * 16 + r, kd = kc * 32 + g * 8 + e;
        const int o = f >> 1, s = f & 1, node = kd >> 2, d = kd & 3;
        const int k = d - s;
        const float v = (k >= 0 && k < 3) ? cw[o * 192 + node * 3 + k] : 0.f;
        wcvc[i] = f2bf(v);
    }
    if (i < 128) biasf[i] = cb[i >> 1];
}

// ---------------- k_attn: attention -> h (bf16, fragment-major) ----------------
// 1024 blocks x 4 waves; wave wv rows 4wv..4wv+3 (f16 staging + fdot2, R18 form).
// h value (row r, node j, d) stored at ushort addr:
//   blk*4096 + (j>>3)*512 + ((j>>1)&3)*128 + r*8 + (j&1)*4 + d
__global__ __launch_bounds__(256, 4) void k_attn(
    const float* __restrict__ x,       // (B,64,2)
    const float* __restrict__ W_gat,   // (4,2)
    const float* __restrict__ a_attn,  // (8,)
    unsigned int* __restrict__ h_frag) // fragment-major bf16 (2 per uint)
{
    __shared__ unsigned short scr16[16 * 256];   // [16 rows][u|v|x0|x1] f16, 8KB

    const int tid = threadIdx.x, lane = tid & 63, wv = tid >> 6;  // wv 0..3
    const int base = blockIdx.x * 16;

    const float Wg00 = W_gat[0], Wg01 = W_gat[1], Wg10 = W_gat[2], Wg11 = W_gat[3];
    const float Wg20 = W_gat[4], Wg21 = W_gat[5], Wg30 = W_gat[6], Wg31 = W_gat[7];
    const float as0 = a_attn[0], as1 = a_attn[1], as2 = a_attn[2], as3 = a_attn[3];
    const float ad0 = a_attn[4], ad1 = a_attn[5], ad2 = a_attn[6], ad3 = a_attn[7];
    const float cs0 = as0 * Wg00 + as1 * Wg10 + as2 * Wg20 + as3 * Wg30;
    const float cs1 = as0 * Wg01 + as1 * Wg11 + as2 * Wg21 + as3 * Wg31;
    const float cd0 = ad0 * Wg00 + ad1 * Wg10 + ad2 * Wg20 + ad3 * Wg30;
    const float cd1 = ad0 * Wg01 + ad1 * Wg11 + ad2 * Wg21 + ad3 * Wg31;
    const float L2E = 1.4426950408889634f;
    const float SL = 0.2f;
    const h2 one2 = {(_Float16)1.0f, (_Float16)1.0f};

    // output uint base offset for this lane's node j = lane
    const int j = lane;
    unsigned int* outp = h_frag + (size_t)blockIdx.x * 2048
                       + (j >> 3) * 256 + ((j >> 1) & 3) * 64 + (j & 1) * 2;

    float2 xv = ((const float2*)x)[(size_t)(base + wv * 4) * 64 + lane];
    #pragma unroll
    for (int t = 0; t < 4; ++t) {
        float2 xv_n;
        if (t < 3) xv_n = ((const float2*)x)[(size_t)(base + wv * 4 + t + 1) * 64 + lane];
        const int lr = wv * 4 + t;

        const float es = xv.x * cs0 + xv.y * cs1;
        const float ed = xv.x * cd0 + xv.y * cd1;
        float M = es;
        #pragma unroll
        for (int m = 32; m; m >>= 1) M = fmaxf(M, __shfl_xor(M, m));
        const float um = (es - M) * L2E;                 // <= 0
        const _Float16 uh = (_Float16)__builtin_amdgcn_exp2f(um);
        const _Float16 vh = (_Float16)__builtin_amdgcn_exp2f(SL * um);
        const float tt = M + ed;
        const float mj = fmaxf(tt, SL * tt);             // lrelu(M+ed) = col max
        const _Float16 Uh = (_Float16)__builtin_amdgcn_exp2f((ed + M - mj) * L2E);
        const _Float16 Vh = (_Float16)__builtin_amdgcn_exp2f((SL * (ed + M) - mj) * L2E);
        const _Float16 x0h = (_Float16)xv.x, x1h = (_Float16)xv.y;

        unsigned short* rowp = scr16 + lr * 256;
        rowp[lane]       = __builtin_bit_cast(unsigned short, uh);
        rowp[64 + lane]  = __builtin_bit_cast(unsigned short, vh);
        rowp[128 + lane] = __builtin_bit_cast(unsigned short, x0h);
        rowp[192 + lane] = __builtin_bit_cast(unsigned short, x1h);

        const h2 UU = (h2){Uh, Uh};
        const h2 VV = (h2){Vh, Vh};
        const uint4* up = (const uint4*)rowp;
        float S = 0.f, A0 = 0.f, A1 = 0.f;
        #pragma unroll 4
        for (int k = 0; k < 8; ++k) {
            const uint4 uq  = up[k];
            const uint4 vq  = up[8 + k];
            const uint4 x0q = up[16 + k];
            const uint4 x1q = up[24 + k];
            const unsigned* ua  = (const unsigned*)&uq;
            const unsigned* va  = (const unsigned*)&vq;
            const unsigned* x0a = (const unsigned*)&x0q;
            const unsigned* x1a = (const unsigned*)&x1q;
            #pragma unroll
            for (int p = 0; p < 4; ++p) {
                const h2 u2 = __builtin_bit_cast(h2, ua[p]);
                const h2 v2 = __builtin_bit_cast(h2, va[p]);
                const h2 P2 = __builtin_elementwise_max(u2 * UU, v2 * VV);
#if __has_builtin(__builtin_amdgcn_fdot2)
                S  = __builtin_amdgcn_fdot2(P2, one2, S, false);
                A0 = __builtin_amdgcn_fdot2(P2, __builtin_bit_cast(h2, x0a[p]), A0, false);
                A1 = __builtin_amdgcn_fdot2(P2, __builtin_bit_cast(h2, x1a[p]), A1, false);
#else
                const h2 xa = __builtin_bit_cast(h2, x0a[p]);
                const h2 xb = __builtin_bit_cast(h2, x1a[p]);
                S  += (float)P2.x + (float)P2.y;
                A0 += (float)P2.x * (float)xa.x + (float)P2.y * (float)xa.y;
                A1 += (float)P2.x * (float)xb.x + (float)P2.y * (float)xb.y;
#endif
            }
        }
        // self term: identical f16 ops -> near-exact cancellation
        const h2 pm = (h2){uh, vh} * (h2){Uh, Vh};
        const _Float16 pSh = (pm.x > pm.y) ? pm.x : pm.y;
        const float pS = (float)pSh;
        S -= pS;
        A0 -= pS * (float)x0h;
        A1 -= pS * (float)x1h;
        const float rs = 1.0f / S;
        const float h0 = (Wg00 * A0 + Wg01 * A1) * rs;
        const float h1 = (Wg10 * A0 + Wg11 * A1) * rs;
        const float h2v = (Wg20 * A0 + Wg21 * A1) * rs;
        const float h3 = (Wg30 * A0 + Wg31 * A1) * rs;
        // fragment-major store (8B): uint addr lr*4 within the lane's slot
        *(uint2*)(outp + lr * 4) = make_uint2(pack2bf(h0, h1), pack2bf(h2v, h3));
        xv = xv_n;
    }
}

// ---------------- k_convdec: conv + decoder (all loads lane-contiguous) -------------
// 1024 blocks x 4 waves, 16 batches. Conv: fb={wv,wv+4}, h from frag-major global.
// L1: nb=8wv..8wv+7. L2: mb={wv,wv+4}. LDS only for flat/hdec transposes (20KB).
__global__ __launch_bounds__(256, 4) void k_convdec(
    const unsigned short* h_bf,              // fragment-major bf16 (aliases dec_out)
    const unsigned short* __restrict__ w1c,  // 128 frags x 512
    const unsigned short* __restrict__ w2c,  // 128 frags x 512
    const unsigned short* __restrict__ wcvc, // 64 frags x 512
    const float* __restrict__ biasf,         // (128,)
    const float* __restrict__ b1,            // (512,)
    const float* __restrict__ b2,            // (128,)
    float* __restrict__ enc_out,             // (B,128) f32
    float* dec_out)                          // (B,128) f32 (aliases h_bf)
{
    __shared__ unsigned short flat_lds[16 * 128];  // bf16 swz, 4KB
    __shared__ unsigned short hdec_lds[16 * 512];  // bf16 swz, 16KB

    const int tid = threadIdx.x, lane = tid & 63, wv = tid >> 6;   // wv 0..3
    const int r = lane & 15, g = lane >> 4;
    const int base = blockIdx.x * 16;
    const int l8 = lane * 8;
    const unsigned short* htile = h_bf + (size_t)blockIdx.x * 4096;

    // ================= conv (as matmul, K=256): fb = wv, wv+4 =================
    f32x4 accc[2];
    accc[0] = (f32x4){0.f, 0.f, 0.f, 0.f};
    accc[1] = (f32x4){0.f, 0.f, 0.f, 0.f};
    #pragma unroll
    for (int kc = 0; kc < 8; ++kc) {
        const bf16x8 hf  = *(const bf16x8*)(htile + kc * 512 + l8);
        const bf16x8 wfa = *(const bf16x8*)(wcvc + ((wv * 8 + kc) << 9) + l8);
        const bf16x8 wfb = *(const bf16x8*)(wcvc + (((wv + 4) * 8 + kc) << 9) + l8);
        accc[0] = __builtin_amdgcn_mfma_f32_16x16x32_bf16(wfa, hf, accc[0], 0, 0, 0);
        accc[1] = __builtin_amdgcn_mfma_f32_16x16x32_bf16(wfb, hf, accc[1], 0, 0, 0);
    }
    #pragma unroll
    for (int q = 0; q < 2; ++q) {
        const int f0 = (wv + q * 4) * 16 + g * 4;
        const float4 bs = *(const float4*)(biasf + f0);
        const float v0 = accc[q][0] + bs.x, v1 = accc[q][1] + bs.y;
        const float v2 = accc[q][2] + bs.z, v3 = accc[q][3] + bs.w;
        *(float4*)(enc_out + (size_t)(base + r) * 128 + f0) = make_float4(v0, v1, v2, v3);
        const int fidx = (r * 128 + f0) ^ SWZ(r);
        *(uint2*)(&flat_lds[fidx]) = make_uint2(pack2bf(v0, v1), pack2bf(v2, v3));
    }
    __syncthreads();

    // ================= decoder layer1: 128 -> 512, relu; nb = 8wv..8wv+7 ==============
    bf16x8 ff1[4];
    #pragma unroll
    for (int kb = 0; kb < 4; ++kb)
        ff1[kb] = *(const bf16x8*)(&flat_lds[(r * 128 + kb * 32 + g * 8) ^ SWZ(r)]);
    #pragma unroll
    for (int t = 0; t < 8; ++t) {
        const int nb = wv * 8 + t;
        f32x4 a1 = (f32x4){0.f, 0.f, 0.f, 0.f};
        #pragma unroll
        for (int kb = 0; kb < 4; ++kb) {
            const bf16x8 wf = *(const bf16x8*)(w1c + (((nb << 2) + kb) << 9) + l8);
            a1 = __builtin_amdgcn_mfma_f32_16x16x32_bf16(wf, ff1[kb], a1, 0, 0, 0);
        }
        const int n0 = nb * 16 + g * 4;
        const float4 bs = *(const float4*)(b1 + n0);
        const float v0 = fmaxf(a1[0] + bs.x, 0.f);
        const float v1 = fmaxf(a1[1] + bs.y, 0.f);
        const float v2 = fmaxf(a1[2] + bs.z, 0.f);
        const float v3 = fmaxf(a1[3] + bs.w, 0.f);
        const int hdidx = (r * 512 + n0) ^ SWZ(r);
        *(uint2*)(&hdec_lds[hdidx]) = make_uint2(pack2bf(v0, v1), pack2bf(v2, v3));
    }
    __syncthreads();

    // ================= decoder layer2: 512 -> 128; mb = wv, wv+4 =================
    f32x4 acc2[2];
    acc2[0] = (f32x4){0.f, 0.f, 0.f, 0.f};
    acc2[1] = (f32x4){0.f, 0.f, 0.f, 0.f};
    #pragma unroll
    for (int np = 0; np < 16; ++np) {
        const bf16x8 hfd = *(const bf16x8*)(&hdec_lds[(r * 512 + np * 32 + g * 8) ^ SWZ(r)]);
        const bf16x8 wfa = *(const bf16x8*)(w2c + (((wv * 16) + np) << 9) + l8);
        const bf16x8 wfb = *(const bf16x8*)(w2c + ((((wv + 4) * 16) + np) << 9) + l8);
        acc2[0] = __builtin_amdgcn_mfma_f32_16x16x32_bf16(wfa, hfd, acc2[0], 0, 0, 0);
        acc2[1] = __builtin_amdgcn_mfma_f32_16x16x32_bf16(wfb, hfd, acc2[1], 0, 0, 0);
    }
    #pragma unroll
    for (int q = 0; q < 2; ++q) {
        const int m0 = (wv + q * 4) * 16 + g * 4;
        const float4 bs = *(const float4*)(b2 + m0);
        *(float4*)(dec_out + (size_t)(base + r) * 128 + m0) =
            make_float4(acc2[q][0] + bs.x, acc2[q][1] + bs.y,
                        acc2[q][2] + bs.z, acc2[q][3] + bs.w);
    }
}

extern "C" void kernel_launch(void* const* d_in, const int* in_sizes, int n_in,
                              void* d_out, int out_size, void* d_ws, size_t ws_size,
                              hipStream_t stream) {
    const float* x      = (const float*)d_in[0];
    const float* W_gat  = (const float*)d_in[1];
    const float* a_attn = (const float*)d_in[2];
    const float* conv_w = (const float*)d_in[3];
    const float* conv_b = (const float*)d_in[4];
    const float* dec_w1 = (const float*)d_in[5];
    const float* dec_b1 = (const float*)d_in[6];
    const float* dec_w2 = (const float*)d_in[7];
    const float* dec_b2 = (const float*)d_in[8];
    float* out = (float*)d_out;

    const int B = in_sizes[0] / 128;                 // 16384
    unsigned short* w1c  = (unsigned short*)d_ws;    // 128 frags x 512
    unsigned short* w2c  = w1c + 128 * 512;          // 128 frags x 512
    unsigned short* wcvc = w2c + 128 * 512;          // 64 frags x 512
    float* biasf = (float*)(wcvc + 64 * 512);        // 128

    // h (fragment-major bf16) lives in the decoded-output region:
    // block t uses bytes [t*8192,(t+1)*8192) and later writes dec rows over the
    // same bytes after its conv loads complete (barrier-ordered within block).
    unsigned short* h_bf = (unsigned short*)(out + (size_t)B * 128);

    k0_prep<<<256, 256, 0, stream>>>(dec_w1, dec_w2, conv_w, conv_b, w1c, w2c, wcvc, biasf);

    k_attn<<<B / 16, 256, 0, stream>>>(x, W_gat, a_attn, (unsigned int*)h_bf);

    k_convdec<<<B / 16, 256, 0, stream>>>(h_bf, w1c, w2c, wcvc, biasf, dec_b1, dec_b2,
                                          out, out + (size_t)B * 128);
}

// Round 22
// 30.954 us; speedup vs baseline: 1.2898x; 1.2898x over previous
//
#include <hip/hip_runtime.h>

// ConvAutoEncoder: B=16384, T=64, C=2, D=4
// out = [encoder_out (B*128 f32) | decoded (B*128 f32)]
// FINAL (R18): fragment-major weights + f16/fdot2 attention staging.
// - Weights pre-permuted so every MFMA weight load is base + lane*16B (1 segment).
// - Attention: (u',v',x0,x1) staged f16 max-normalized (32 ds_read_b128/row),
//   packed-f16 math + dot2 accumulate; self-term subtracted with matching f16 ops.

typedef __attribute__((ext_vector_type(8))) short bf16x8;
typedef __attribute__((ext_vector_type(4))) float f32x4;
typedef _Float16 h2 __attribute__((ext_vector_type(2)));

__device__ __forceinline__ unsigned short f2bf(float f) {
    unsigned int u = __builtin_bit_cast(unsigned int, f);
    return (unsigned short)((u + 0x7FFFu + ((u >> 16) & 1u)) >> 16);
}
__device__ __forceinline__ unsigned int pack2bf(float a, float b) {
    return (unsigned int)f2bf(a) | ((unsigned int)f2bf(b) << 16);
}

#define SWZ(row) (((row) & 7) << 3)   // ushort-index XOR == byte XOR ((row&7)<<4)

// ---------------- kernel 0: weight prep (fragment-major permutation) ----------------
__global__ void k0_prep(const float* __restrict__ w1, const float* __restrict__ w2,
                        const float* __restrict__ cw, const float* __restrict__ cb,
                        unsigned short* __restrict__ w1c, unsigned short* __restrict__ w2c,
                        unsigned short* __restrict__ wcvc, float* __restrict__ biasf) {
    const int i = blockIdx.x * 256 + threadIdx.x;      // 0..65535
    const int rem = i & 511, ln = rem >> 3, e = rem & 7;
    const int r = ln & 15, g = ln >> 4;
    {   // w1c (65536)
        const int frag = i >> 9, nb = frag >> 2, kb = frag & 3;
        w1c[i] = f2bf(w1[(nb * 16 + r) * 128 + kb * 32 + g * 8 + e]);
    }
    {   // w2c (65536)
        const int frag = i >> 9, mb = frag >> 4, np = frag & 15;
        w2c[i] = f2bf(w2[(mb * 16 + r) * 512 + np * 32 + g * 8 + e]);
    }
    if (i < 32768) {   // wcvc
        const int frag = i >> 9, fb = frag >> 3, kc = frag & 7;
        const int f = fb * 16 + r, kd = kc * 32 + g * 8 + e;
        const int o = f >> 1, s = f & 1, node = kd >> 2, d = kd & 3;
        const int k = d - s;
        const float v = (k >= 0 && k < 3) ? cw[o * 192 + node * 3 + k] : 0.f;
        wcvc[i] = f2bf(v);
    }
    if (i < 128) biasf[i] = cb[i >> 1];
}

// ---------------- fused kernel ----------------
// 4 waves, 16 batches/block. Attention: wave wv rows 4wv..4wv+3, f16 staging + fdot2.
// Conv: fb={wv,wv+4}. L1: nb=8wv..8wv+7. L2: mb={wv,wv+4}. Fragment-major weights.
__global__ __launch_bounds__(256, 4) void k_fused(
    const float* __restrict__ x,             // (B,64,2)
    const float* __restrict__ W_gat,         // (4,2)
    const float* __restrict__ a_attn,        // (8,)
    const unsigned short* __restrict__ w1c,  // 128 frags x 512
    const unsigned short* __restrict__ w2c,  // 128 frags x 512
    const unsigned short* __restrict__ wcvc, // 64 frags x 512
    const float* __restrict__ biasf,         // (128,)
    const float* __restrict__ b1,            // (512,)
    const float* __restrict__ b2,            // (128,)
    float* __restrict__ enc_out,             // (B,128) f32
    float* __restrict__ dec_out)             // (B,128) f32
{
    __shared__ __align__(16) unsigned char smem[28672];
    unsigned short* h_lds    = (unsigned short*)smem;            // [16][256] bf16 swz, 8KB
    unsigned short* flat_lds = (unsigned short*)(smem + 8192);   // [16][128] bf16 swz, 4KB
    unsigned short* scr16    = (unsigned short*)(smem + 12288);  // [16 rows][256] f16, 8KB } aliased
    unsigned short* hdec_lds = (unsigned short*)(smem + 12288);  // [16][512] bf16 swz, 16KB }

    const int tid = threadIdx.x, lane = tid & 63, wv = tid >> 6;  // wv 0..3
    const int r = lane & 15, g = lane >> 4;
    const int base = blockIdx.x * 16;
    const int l8 = lane * 8;

    // ================= attention (4 rows per wave, f16 staging + fdot2) ==============
    {
        const float Wg00 = W_gat[0], Wg01 = W_gat[1], Wg10 = W_gat[2], Wg11 = W_gat[3];
        const float Wg20 = W_gat[4], Wg21 = W_gat[5], Wg30 = W_gat[6], Wg31 = W_gat[7];
        const float as0 = a_attn[0], as1 = a_attn[1], as2 = a_attn[2], as3 = a_attn[3];
        const float ad0 = a_attn[4], ad1 = a_attn[5], ad2 = a_attn[6], ad3 = a_attn[7];
        const float cs0 = as0 * Wg00 + as1 * Wg10 + as2 * Wg20 + as3 * Wg30;
        const float cs1 = as0 * Wg01 + as1 * Wg11 + as2 * Wg21 + as3 * Wg31;
        const float cd0 = ad0 * Wg00 + ad1 * Wg10 + ad2 * Wg20 + ad3 * Wg30;
        const float cd1 = ad0 * Wg01 + ad1 * Wg11 + ad2 * Wg21 + ad3 * Wg31;
        const float L2E = 1.4426950408889634f;
        const float SL = 0.2f;

        // per-row saved f16 state: (u,v), (U'',V''), (x0,x1)
        h2 uvh[4], UVh[4], xyh[4];
        float xf0[4], xf1[4];

        #pragma unroll
        for (int t = 0; t < 4; ++t) {
            const float2 xv = ((const float2*)x)[(size_t)(base + wv * 4 + t) * 64 + lane];
            const float es = xv.x * cs0 + xv.y * cs1;
            const float ed = xv.x * cd0 + xv.y * cd1;
            // wave max of es (per batch)
            float M = es;
            #pragma unroll
            for (int m = 32; m; m >>= 1) M = fmaxf(M, __shfl_xor(M, m));
            const float um = (es - M) * L2E;                 // <= 0
            const _Float16 uh = (_Float16)__builtin_amdgcn_exp2f(um);
            const _Float16 vh = (_Float16)__builtin_amdgcn_exp2f(SL * um);
            const float tt = M + ed;
            const float mj = fmaxf(tt, SL * tt);             // lrelu(M+ed) = col max exp
            const _Float16 Uh = (_Float16)__builtin_amdgcn_exp2f((ed + M - mj) * L2E);
            const _Float16 Vh = (_Float16)__builtin_amdgcn_exp2f((SL * (ed + M) - mj) * L2E);
            const _Float16 x0h = (_Float16)xv.x, x1h = (_Float16)xv.y;

            unsigned short* rowp = scr16 + (wv * 4 + t) * 256;
            rowp[lane]       = __builtin_bit_cast(unsigned short, uh);
            rowp[64 + lane]  = __builtin_bit_cast(unsigned short, vh);
            rowp[128 + lane] = __builtin_bit_cast(unsigned short, x0h);
            rowp[192 + lane] = __builtin_bit_cast(unsigned short, x1h);

            uvh[t] = (h2){uh, vh};
            UVh[t] = (h2){Uh, Vh};
            xyh[t] = (h2){x0h, x1h};
            xf0[t] = (float)x0h; xf1[t] = (float)x1h;
        }

        const h2 one2 = {(_Float16)1.0f, (_Float16)1.0f};

        #pragma unroll
        for (int t = 0; t < 4; ++t) {
            const uint4* up = (const uint4*)(scr16 + (wv * 4 + t) * 256);
            const h2 UU = (h2){UVh[t].x, UVh[t].x};
            const h2 VV = (h2){UVh[t].y, UVh[t].y};
            float S = 0.f, A0 = 0.f, A1 = 0.f;
            #pragma unroll 4
            for (int k = 0; k < 8; ++k) {
                const uint4 uq  = up[k];          // 8 neighbors' u
                const uint4 vq  = up[8 + k];      // v
                const uint4 x0q = up[16 + k];     // x0
                const uint4 x1q = up[24 + k];     // x1
                const unsigned* ua  = (const unsigned*)&uq;
                const unsigned* va  = (const unsigned*)&vq;
                const unsigned* x0a = (const unsigned*)&x0q;
                const unsigned* x1a = (const unsigned*)&x1q;
                #pragma unroll
                for (int p = 0; p < 4; ++p) {
                    const h2 u2  = __builtin_bit_cast(h2, ua[p]);
                    const h2 v2  = __builtin_bit_cast(h2, va[p]);
                    const h2 P2  = __builtin_elementwise_max(u2 * UU, v2 * VV);
#if __has_builtin(__builtin_amdgcn_fdot2)
                    S  = __builtin_amdgcn_fdot2(P2, one2, S, false);
                    A0 = __builtin_amdgcn_fdot2(P2, __builtin_bit_cast(h2, x0a[p]), A0, false);
                    A1 = __builtin_amdgcn_fdot2(P2, __builtin_bit_cast(h2, x1a[p]), A1, false);
#else
                    const h2 xa = __builtin_bit_cast(h2, x0a[p]);
                    const h2 xb = __builtin_bit_cast(h2, x1a[p]);
                    S  += (float)P2.x + (float)P2.y;
                    A0 += (float)P2.x * (float)xa.x + (float)P2.y * (float)xa.y;
                    A1 += (float)P2.x * (float)xb.x + (float)P2.y * (float)xb.y;
#endif
                }
            }
            // self term: identical f16 ops -> near-exact cancellation
            const h2 pm = uvh[t] * UVh[t];                   // (u*U'', v*V'')
            const _Float16 pSh = (pm.x > pm.y) ? pm.x : pm.y;
            const float pS = (float)pSh;
            S -= pS;
            A0 -= pS * xf0[t];
            A1 -= pS * xf1[t];
            const float rs = 1.0f / S;
            const float h0 = (Wg00 * A0 + Wg01 * A1) * rs;
            const float h1 = (Wg10 * A0 + Wg11 * A1) * rs;
            const float h2v = (Wg20 * A0 + Wg21 * A1) * rs;
            const float h3 = (Wg30 * A0 + Wg31 * A1) * rs;
            const int lr = wv * 4 + t;
            const int hidx = (lr * 256 + lane * 4) ^ SWZ(lr);
            *(uint2*)(&h_lds[hidx]) = make_uint2(pack2bf(h0, h1), pack2bf(h2v, h3));
        }
    }
    __syncthreads();

    // ================= conv (as matmul, K=256): fb = wv, wv+4 =================
    f32x4 accc[2];
    accc[0] = (f32x4){0.f, 0.f, 0.f, 0.f};
    accc[1] = (f32x4){0.f, 0.f, 0.f, 0.f};
    #pragma unroll
    for (int kc = 0; kc < 8; ++kc) {
        const bf16x8 hf  = *(const bf16x8*)(&h_lds[(r * 256 + kc * 32 + g * 8) ^ SWZ(r)]);
        const bf16x8 wfa = *(const bf16x8*)(wcvc + ((wv * 8 + kc) << 9) + l8);
        const bf16x8 wfb = *(const bf16x8*)(wcvc + (((wv + 4) * 8 + kc) << 9) + l8);
        accc[0] = __builtin_amdgcn_mfma_f32_16x16x32_bf16(wfa, hf, accc[0], 0, 0, 0);
        accc[1] = __builtin_amdgcn_mfma_f32_16x16x32_bf16(wfb, hf, accc[1], 0, 0, 0);
    }
    #pragma unroll
    for (int q = 0; q < 2; ++q) {
        const int f0 = (wv + q * 4) * 16 + g * 4;
        const float4 bs = *(const float4*)(biasf + f0);
        const float v0 = accc[q][0] + bs.x, v1 = accc[q][1] + bs.y;
        const float v2 = accc[q][2] + bs.z, v3 = accc[q][3] + bs.w;
        *(float4*)(enc_out + (size_t)(base + r) * 128 + f0) = make_float4(v0, v1, v2, v3);
        const int fidx = (r * 128 + f0) ^ SWZ(r);
        *(uint2*)(&flat_lds[fidx]) = make_uint2(pack2bf(v0, v1), pack2bf(v2, v3));
    }
    __syncthreads();

    // ================= decoder layer1: 128 -> 512, relu; nb = 8wv..8wv+7 =================
    bf16x8 ff1[4];
    #pragma unroll
    for (int kb = 0; kb < 4; ++kb)
        ff1[kb] = *(const bf16x8*)(&flat_lds[(r * 128 + kb * 32 + g * 8) ^ SWZ(r)]);
    #pragma unroll
    for (int t = 0; t < 8; ++t) {
        const int nb = wv * 8 + t;
        f32x4 a1 = (f32x4){0.f, 0.f, 0.f, 0.f};
        #pragma unroll
        for (int kb = 0; kb < 4; ++kb) {
            const bf16x8 wf = *(const bf16x8*)(w1c + (((nb << 2) + kb) << 9) + l8);
            a1 = __builtin_amdgcn_mfma_f32_16x16x32_bf16(wf, ff1[kb], a1, 0, 0, 0);
        }
        const int n0 = nb * 16 + g * 4;
        const float4 bs = *(const float4*)(b1 + n0);
        const float v0 = fmaxf(a1[0] + bs.x, 0.f);
        const float v1 = fmaxf(a1[1] + bs.y, 0.f);
        const float v2 = fmaxf(a1[2] + bs.z, 0.f);
        const float v3 = fmaxf(a1[3] + bs.w, 0.f);
        const int hdidx = (r * 512 + n0) ^ SWZ(r);
        *(uint2*)(&hdec_lds[hdidx]) = make_uint2(pack2bf(v0, v1), pack2bf(v2, v3));
    }
    __syncthreads();

    // ================= decoder layer2: 512 -> 128; mb = wv, wv+4 =================
    f32x4 acc2[2];
    acc2[0] = (f32x4){0.f, 0.f, 0.f, 0.f};
    acc2[1] = (f32x4){0.f, 0.f, 0.f, 0.f};
    #pragma unroll
    for (int np = 0; np < 16; ++np) {
        const bf16x8 hfd = *(const bf16x8*)(&hdec_lds[(r * 512 + np * 32 + g * 8) ^ SWZ(r)]);
        const bf16x8 wfa = *(const bf16x8*)(w2c + (((wv * 16) + np) << 9) + l8);
        const bf16x8 wfb = *(const bf16x8*)(w2c + ((((wv + 4) * 16) + np) << 9) + l8);
        acc2[0] = __builtin_amdgcn_mfma_f32_16x16x32_bf16(wfa, hfd, acc2[0], 0, 0, 0);
        acc2[1] = __builtin_amdgcn_mfma_f32_16x16x32_bf16(wfb, hfd, acc2[1], 0, 0, 0);
    }
    #pragma unroll
    for (int q = 0; q < 2; ++q) {
        const int m0 = (wv + q * 4) * 16 + g * 4;
        const float4 bs = *(const float4*)(b2 + m0);
        *(float4*)(dec_out + (size_t)(base + r) * 128 + m0) =
            make_float4(acc2[q][0] + bs.x, acc2[q][1] + bs.y,
                        acc2[q][2] + bs.z, acc2[q][3] + bs.w);
    }
}

extern "C" void kernel_launch(void* const* d_in, const int* in_sizes, int n_in,
                              void* d_out, int out_size, void* d_ws, size_t ws_size,
                              hipStream_t stream) {
    const float* x      = (const float*)d_in[0];
    const float* W_gat  = (const float*)d_in[1];
    const float* a_attn = (const float*)d_in[2];
    const float* conv_w = (const float*)d_in[3];
    const float* conv_b = (const float*)d_in[4];
    const float* dec_w1 = (const float*)d_in[5];
    const float* dec_b1 = (const float*)d_in[6];
    const float* dec_w2 = (const float*)d_in[7];
    const float* dec_b2 = (const float*)d_in[8];
    float* out = (float*)d_out;

    const int B = in_sizes[0] / 128;                 // 16384
    unsigned short* w1c  = (unsigned short*)d_ws;    // 128 frags x 512
    unsigned short* w2c  = w1c + 128 * 512;          // 128 frags x 512
    unsigned short* wcvc = w2c + 128 * 512;          // 64 frags x 512
    float* biasf = (float*)(wcvc + 64 * 512);        // 128

    k0_prep<<<256, 256, 0, stream>>>(dec_w1, dec_w2, conv_w, conv_b, w1c, w2c, wcvc, biasf);

    k_fused<<<B / 16, 256, 0, stream>>>(x, W_gat, a_attn, w1c, w2c, wcvc, biasf,
                                        dec_b1, dec_b2, out, out + (size_t)B * 128);
}